// Round 6
// baseline (73.765 us; speedup 1.0000x reference)
//
#include <hip/hip_runtime.h>

#define SIREN_K 4
#define SIREN_H 32
#define SIREN_C 512
#define SIREN_C4 128   // C / 4
#define OMEGA0 30.0f

typedef float f32x4 __attribute__((ext_vector_type(4)));

// ---------------------------------------------------------------------------
// Kernel 1: build the [K][C] SIREN filter table (tiny MLP, one block, 512 thr).
// ---------------------------------------------------------------------------
__global__ void siren_table_kernel(const float* __restrict__ w0, const float* __restrict__ b0,
                                   const float* __restrict__ w1, const float* __restrict__ b1,
                                   const float* __restrict__ w2, const float* __restrict__ b2,
                                   const float* __restrict__ w3, const float* __restrict__ b3,
                                   float* __restrict__ ker /* [K][C] */) {
    __shared__ float bufA[SIREN_K][SIREN_H];
    __shared__ float bufB[SIREN_K][SIREN_H];
    const int tid = threadIdx.x;

    if (tid < SIREN_K * SIREN_H) {
        int k = tid >> 5, j = tid & 31;
        float pos = -1.0f + (2.0f / (float)(SIREN_K - 1)) * (float)k;
        if (k == SIREN_K - 1) pos = 1.0f;  // linspace endpoint exact
        pos *= OMEGA0;
        bufA[k][j] = sinf(pos * w0[j] + b0[j]);
    }
    __syncthreads();

    if (tid < SIREN_K * SIREN_H) {
        int k = tid >> 5, j = tid & 31;
        float s = b1[j];
        #pragma unroll
        for (int i = 0; i < SIREN_H; ++i) s += bufA[k][i] * w1[j * SIREN_H + i];
        bufB[k][j] = sinf(s);
    }
    __syncthreads();

    if (tid < SIREN_K * SIREN_H) {
        int k = tid >> 5, j = tid & 31;
        float s = b2[j];
        #pragma unroll
        for (int i = 0; i < SIREN_H; ++i) s += bufB[k][i] * w2[j * SIREN_H + i];
        bufA[k][j] = sinf(s);
    }
    __syncthreads();

    const int c = tid;  // 512 threads, one channel each
    if (c < SIREN_C) {
        const f32x4* w3v = (const f32x4*)(w3 + c * SIREN_H);
        f32x4 wrow[SIREN_H / 4];
        #pragma unroll
        for (int q = 0; q < SIREN_H / 4; ++q) wrow[q] = w3v[q];
        #pragma unroll
        for (int k = 0; k < SIREN_K; ++k) {
            float s = b3[c];
            #pragma unroll
            for (int q = 0; q < SIREN_H / 4; ++q) {
                s += bufA[k][4*q+0] * wrow[q].x + bufA[k][4*q+1] * wrow[q].y
                   + bufA[k][4*q+2] * wrow[q].z + bufA[k][4*q+3] * wrow[q].w;
            }
            ker[k * SIREN_C + c] = s;
        }
    }
}

// ---------------------------------------------------------------------------
// Kernel 2: depthwise strided conv — exact grid, zero loop, 4 outputs/thread.
// out4[idx] = sum_k x4[(idx>>7)*512 + k*128 + (idx&127)] * ker4[k*128 + (idx&127)]
// 4096 blocks x 256 threads; thread handles idx0 = bid*1024+tid + {0,256,512,768}.
// All four share c4 = tid&127, so one weight set serves all outputs.
// 16 independent global loads in flight per thread (256 B MLP depth).
// ---------------------------------------------------------------------------
__global__ void __launch_bounds__(256) dwconv_kernel(const f32x4* __restrict__ x4,
                                                     const f32x4* __restrict__ ker4,
                                                     f32x4* __restrict__ out4) {
    const int tid = threadIdx.x;
    const int idx0 = blockIdx.x * 1024 + tid;
    const int c4 = tid & (SIREN_C4 - 1);

    // weights first (L2-hot after kernel 1 — returns fast)
    const f32x4 wv0 = ker4[0 * SIREN_C4 + c4];
    const f32x4 wv1 = ker4[1 * SIREN_C4 + c4];
    const f32x4 wv2 = ker4[2 * SIREN_C4 + c4];
    const f32x4 wv3 = ker4[3 * SIREN_C4 + c4];

    const f32x4* xp0 = x4 + (idx0 >> 7) * (4 * SIREN_C4) + c4;           // out idx0
    const f32x4* xp1 = x4 + ((idx0 + 256) >> 7) * (4 * SIREN_C4) + c4;   // out idx0+256
    const f32x4* xp2 = x4 + ((idx0 + 512) >> 7) * (4 * SIREN_C4) + c4;   // out idx0+512
    const f32x4* xp3 = x4 + ((idx0 + 768) >> 7) * (4 * SIREN_C4) + c4;   // out idx0+768

    // 16 independent loads — all issued before any use
    const f32x4 a0 = xp0[0 * SIREN_C4];
    const f32x4 b0 = xp0[1 * SIREN_C4];
    const f32x4 c0 = xp0[2 * SIREN_C4];
    const f32x4 d0 = xp0[3 * SIREN_C4];
    const f32x4 a1 = xp1[0 * SIREN_C4];
    const f32x4 b1 = xp1[1 * SIREN_C4];
    const f32x4 c1 = xp1[2 * SIREN_C4];
    const f32x4 d1 = xp1[3 * SIREN_C4];
    const f32x4 a2 = xp2[0 * SIREN_C4];
    const f32x4 b2 = xp2[1 * SIREN_C4];
    const f32x4 c2 = xp2[2 * SIREN_C4];
    const f32x4 d2 = xp2[3 * SIREN_C4];
    const f32x4 a3 = xp3[0 * SIREN_C4];
    const f32x4 b3 = xp3[1 * SIREN_C4];
    const f32x4 c3 = xp3[2 * SIREN_C4];
    const f32x4 d3 = xp3[3 * SIREN_C4];

    out4[idx0 +   0] = a0 * wv0 + b0 * wv1 + c0 * wv2 + d0 * wv3;
    out4[idx0 + 256] = a1 * wv0 + b1 * wv1 + c1 * wv2 + d1 * wv3;
    out4[idx0 + 512] = a2 * wv0 + b2 * wv1 + c2 * wv2 + d2 * wv3;
    out4[idx0 + 768] = a3 * wv0 + b3 * wv1 + c3 * wv2 + d3 * wv3;
}

extern "C" void kernel_launch(void* const* d_in, const int* in_sizes, int n_in,
                              void* d_out, int out_size, void* d_ws, size_t ws_size,
                              hipStream_t stream) {
    // Input order (setup_inputs): x, w0, b0, w1, b1, w2, b2, w3, b3, target_len
    const float* x  = (const float*)d_in[0];
    const float* w0 = (const float*)d_in[1];
    const float* b0 = (const float*)d_in[2];
    const float* w1 = (const float*)d_in[3];
    const float* b1 = (const float*)d_in[4];
    const float* w2 = (const float*)d_in[5];
    const float* b2 = (const float*)d_in[6];
    const float* w3 = (const float*)d_in[7];
    const float* b3 = (const float*)d_in[8];

    float* ker = (float*)d_ws;  // K*C floats = 8 KiB

    siren_table_kernel<<<1, 512, 0, stream>>>(w0, b0, w1, b1, w2, b2, w3, b3, ker);

    const int total4 = out_size / 4;        // 4,194,304 f32x4 outputs
    const int blocks = total4 / 1024;       // 4096, exact (no tail)
    dwconv_kernel<<<blocks, 256, 0, stream>>>((const f32x4*)x, (const f32x4*)ker,
                                              (f32x4*)d_out);
}

// Round 7
// 59.541 us; speedup vs baseline: 1.2389x; 1.2389x over previous
//
#include <hip/hip_runtime.h>

#define SIREN_K 4
#define SIREN_H 32
#define SIREN_C 512
#define SIREN_C4 128   // C / 4
#define OMEGA0 30.0f

typedef float f32x4 __attribute__((ext_vector_type(4)));

// ---------------------------------------------------------------------------
// Kernel 1: build the [K][C] SIREN filter table (tiny MLP, one block, 512 thr).
// ---------------------------------------------------------------------------
__global__ void siren_table_kernel(const float* __restrict__ w0, const float* __restrict__ b0,
                                   const float* __restrict__ w1, const float* __restrict__ b1,
                                   const float* __restrict__ w2, const float* __restrict__ b2,
                                   const float* __restrict__ w3, const float* __restrict__ b3,
                                   float* __restrict__ ker /* [K][C] */) {
    __shared__ float bufA[SIREN_K][SIREN_H];
    __shared__ float bufB[SIREN_K][SIREN_H];
    const int tid = threadIdx.x;

    if (tid < SIREN_K * SIREN_H) {
        int k = tid >> 5, j = tid & 31;
        float pos = -1.0f + (2.0f / (float)(SIREN_K - 1)) * (float)k;
        if (k == SIREN_K - 1) pos = 1.0f;  // linspace endpoint exact
        pos *= OMEGA0;
        bufA[k][j] = sinf(pos * w0[j] + b0[j]);
    }
    __syncthreads();

    if (tid < SIREN_K * SIREN_H) {
        int k = tid >> 5, j = tid & 31;
        float s = b1[j];
        #pragma unroll
        for (int i = 0; i < SIREN_H; ++i) s += bufA[k][i] * w1[j * SIREN_H + i];
        bufB[k][j] = sinf(s);
    }
    __syncthreads();

    if (tid < SIREN_K * SIREN_H) {
        int k = tid >> 5, j = tid & 31;
        float s = b2[j];
        #pragma unroll
        for (int i = 0; i < SIREN_H; ++i) s += bufB[k][i] * w2[j * SIREN_H + i];
        bufA[k][j] = sinf(s);
    }
    __syncthreads();

    const int c = tid;  // 512 threads, one channel each
    if (c < SIREN_C) {
        const f32x4* w3v = (const f32x4*)(w3 + c * SIREN_H);
        f32x4 wrow[SIREN_H / 4];
        #pragma unroll
        for (int q = 0; q < SIREN_H / 4; ++q) wrow[q] = w3v[q];
        #pragma unroll
        for (int k = 0; k < SIREN_K; ++k) {
            float s = b3[c];
            #pragma unroll
            for (int q = 0; q < SIREN_H / 4; ++q) {
                s += bufA[k][4*q+0] * wrow[q].x + bufA[k][4*q+1] * wrow[q].y
                   + bufA[k][4*q+2] * wrow[q].z + bufA[k][4*q+3] * wrow[q].w;
            }
            ker[k * SIREN_C + c] = s;
        }
    }
}

// ---------------------------------------------------------------------------
// Kernel 2: depthwise strided conv — exact grid, zero loop, 2 outputs/thread.
// out4[idx] = sum_k x4[(idx>>7)*512 + k*128 + (idx&127)] * ker4[k*128 + (idx&127)]
// 8192 blocks x 256 threads; thread handles idx0 = bid*512+tid and idx0+256.
// (idx0+256) keeps the same c4, so one weight set serves both outputs.
// 8 independent x-loads in flight per thread (128 B MLP depth).
// NT loads on x (read-once, 256 MiB — don't pollute L2/L3) and NT stores on
// out (write-once, never read back by the kernel).
// ---------------------------------------------------------------------------
__global__ void __launch_bounds__(256) dwconv_kernel(const f32x4* __restrict__ x4,
                                                     const f32x4* __restrict__ ker4,
                                                     f32x4* __restrict__ out4) {
    const int tid = threadIdx.x;
    const int idx0 = blockIdx.x * 512 + tid;
    const int idx1 = idx0 + 256;
    const int c4 = tid & (SIREN_C4 - 1);

    const int bl0 = idx0 >> 7;
    const int bl1 = idx1 >> 7;
    const f32x4* xp0 = x4 + bl0 * (4 * SIREN_C4) + c4;
    const f32x4* xp1 = x4 + bl1 * (4 * SIREN_C4) + c4;

    // 8 independent non-temporal loads — issue all before any use
    const f32x4 a0 = __builtin_nontemporal_load(&xp0[0 * SIREN_C4]);
    const f32x4 b0 = __builtin_nontemporal_load(&xp0[1 * SIREN_C4]);
    const f32x4 c0 = __builtin_nontemporal_load(&xp0[2 * SIREN_C4]);
    const f32x4 d0 = __builtin_nontemporal_load(&xp0[3 * SIREN_C4]);
    const f32x4 a1 = __builtin_nontemporal_load(&xp1[0 * SIREN_C4]);
    const f32x4 b1 = __builtin_nontemporal_load(&xp1[1 * SIREN_C4]);
    const f32x4 c1 = __builtin_nontemporal_load(&xp1[2 * SIREN_C4]);
    const f32x4 d1 = __builtin_nontemporal_load(&xp1[3 * SIREN_C4]);

    // weights: normal loads (tiny, L2-hot, shared by all blocks)
    const f32x4 wv0 = ker4[0 * SIREN_C4 + c4];
    const f32x4 wv1 = ker4[1 * SIREN_C4 + c4];
    const f32x4 wv2 = ker4[2 * SIREN_C4 + c4];
    const f32x4 wv3 = ker4[3 * SIREN_C4 + c4];

    f32x4 o0 = a0 * wv0 + b0 * wv1 + c0 * wv2 + d0 * wv3;
    f32x4 o1 = a1 * wv0 + b1 * wv1 + c1 * wv2 + d1 * wv3;
    __builtin_nontemporal_store(o0, &out4[idx0]);
    __builtin_nontemporal_store(o1, &out4[idx1]);
}

extern "C" void kernel_launch(void* const* d_in, const int* in_sizes, int n_in,
                              void* d_out, int out_size, void* d_ws, size_t ws_size,
                              hipStream_t stream) {
    // Input order (setup_inputs): x, w0, b0, w1, b1, w2, b2, w3, b3, target_len
    const float* x  = (const float*)d_in[0];
    const float* w0 = (const float*)d_in[1];
    const float* b0 = (const float*)d_in[2];
    const float* w1 = (const float*)d_in[3];
    const float* b1 = (const float*)d_in[4];
    const float* w2 = (const float*)d_in[5];
    const float* b2 = (const float*)d_in[6];
    const float* w3 = (const float*)d_in[7];
    const float* b3 = (const float*)d_in[8];

    float* ker = (float*)d_ws;  // K*C floats = 8 KiB

    siren_table_kernel<<<1, 512, 0, stream>>>(w0, b0, w1, b1, w2, b2, w3, b3, ker);

    const int total4 = out_size / 4;        // 4,194,304 f32x4 outputs
    const int blocks = total4 / 512;        // 8192, exact (no tail)
    dwconv_kernel<<<blocks, 256, 0, stream>>>((const f32x4*)x, (const f32x4*)ker,
                                              (f32x4*)d_out);
}